// Round 3
// baseline (443.829 us; speedup 1.0000x reference)
//
#include <hip/hip_runtime.h>
#include <stdint.h>

#define NPTS 16384
#define CFEAT 256
#define KNN 32
#define RR_HI 0.0900101f  // fp32 prefilter band: 0.09 + 1e-5 (fp32 d2 err <= ~4.4e-7)

typedef __attribute__((ext_vector_type(8))) short short8;
typedef __attribute__((ext_vector_type(4))) float floatx4;

__device__ __forceinline__ uint32_t f2bf(uint32_t u) {  // RNE fp32->bf16 (finite inputs)
  return (u + 0x7fffu + ((u >> 16) & 1u)) >> 16;
}

// ---------------------------------------------------------------------------
// K0: fp32 -> bf16 conversion (feats, W). 4 floats/thread.
// ---------------------------------------------------------------------------
__global__ __launch_bounds__(256) void k_cvt(const float* __restrict__ src,
                                             uint16_t* __restrict__ dst, int n4) {
  int i = blockIdx.x * 256 + threadIdx.x;
  if (i >= n4) return;
  uint4 u = ((const uint4*)src)[i];
  uint32_t lo = f2bf(u.x) | (f2bf(u.y) << 16);
  uint32_t hi = f2bf(u.z) | (f2bf(u.w) << 16);
  ((uint2*)dst)[i] = make_uint2(lo, hi);
}

// ---------------------------------------------------------------------------
// K1: brute-force ball query. fp32 subtraction-form prefilter; candidates
// within the band get exact fp64 d2 (fp32 inputs -> diffs/products exact in
// fp64; matches a float64-accurate ordering). Key = (d2 bits & ~0x3FFF) | idx.
// grid = (16 query-blocks x 1024q, 32 candidate-chunks x 512), block = 256,
// 4 queries/thread (amortizes LDS reads).
// ---------------------------------------------------------------------------
__global__ __launch_bounds__(256) void k_filter(const float* __restrict__ pts,
                                                uint32_t* __restrict__ cnt,
                                                uint64_t* __restrict__ pairs,
                                                int cap) {
  __shared__ float4 sp[512];
  const int t = threadIdx.x;
  const int cbase = blockIdx.y * 512;
  for (int p = t; p < 512; p += 256) {
    sp[p] = make_float4(pts[3 * (cbase + p)], pts[3 * (cbase + p) + 1],
                        pts[3 * (cbase + p) + 2], 0.f);
  }
  __syncthreads();
  const int qbase = blockIdx.x * 1024 + t;
  float qx[4], qy[4], qz[4];
  #pragma unroll
  for (int i = 0; i < 4; ++i) {
    const int q = qbase + i * 256;
    qx[i] = pts[3 * q]; qy[i] = pts[3 * q + 1]; qz[i] = pts[3 * q + 2];
  }
  for (int j = 0; j < 512; ++j) {
    const float4 p = sp[j];
    #pragma unroll
    for (int i = 0; i < 4; ++i) {
      const float dx = qx[i] - p.x, dy = qy[i] - p.y, dz = qz[i] - p.z;
      const float d2 = __fmaf_rn(dx, dx, __fmaf_rn(dy, dy, __fmul_rn(dz, dz)));
      if (d2 <= RR_HI) {
        const double ddx = (double)qx[i] - (double)p.x;
        const double ddy = (double)qy[i] - (double)p.y;
        const double ddz = (double)qz[i] - (double)p.z;
        const double dd2 = fma(ddx, ddx, fma(ddy, ddy, ddz * ddz));
        if (dd2 <= 0.3 * 0.3) {  // exact double 0.09
          const int q = qbase + i * 256;
          const uint32_t pos = atomicAdd(&cnt[q], 1u);
          if ((int)pos < cap) {
            const uint64_t b = (uint64_t)__double_as_longlong(dd2);  // dd2 >= 0
            pairs[(size_t)q * cap + pos] = (b & ~0x3FFFull) | (uint32_t)(cbase + j);
          }
        }
      }
    }
  }
}

// ---------------------------------------------------------------------------
// K2: per query, final 32 indices.
// c <= 32: all in-radius (order-invariant under max-pool) + 0-padding
//          (matches the reference's out-of-radius -> index 0 replacement).
// c  > 32: 32 smallest (d2, idx) keys via wave-wide repeated argmin.
// block = 256 (one query per wave).
// ---------------------------------------------------------------------------
__global__ __launch_bounds__(256) void k_select(const uint32_t* __restrict__ cnt,
                                                const uint64_t* __restrict__ pairs,
                                                uint32_t* __restrict__ sel,
                                                int cap) {
  const int t = threadIdx.x;
  const int q = blockIdx.x * 4 + (t >> 6);
  const int lane = t & 63;
  int c = (int)cnt[q];
  if (c > cap) c = cap;
  const uint64_t* pp = pairs + (size_t)q * cap;
  if (c <= KNN) {
    if (lane < KNN) sel[q * KNN + lane] = (lane < c) ? (uint32_t)(pp[lane] & 0x3FFFull) : 0u;
    return;
  }
  const uint64_t INVALID = ~0ull;
  uint64_t k0 = (lane < c) ? pp[lane] : INVALID;
  uint64_t k1 = (lane + 64 < c) ? pp[lane + 64] : INVALID;
  uint64_t k2 = (lane + 128 < c) ? pp[lane + 128] : INVALID;
  uint64_t k3 = (lane + 192 < c) ? pp[lane + 192] : INVALID;
  for (int it = 0; it < KNN; ++it) {
    uint64_t a = k0 < k1 ? k0 : k1;
    uint64_t b = k2 < k3 ? k2 : k3;
    uint64_t m = a < b ? a : b;
    #pragma unroll
    for (int off = 1; off < 64; off <<= 1) {
      uint64_t o = (uint64_t)__shfl_xor((unsigned long long)m, off, 64);
      m = o < m ? o : m;
    }
    if (k0 == m) k0 = INVALID;
    else if (k1 == m) k1 = INVALID;
    else if (k2 == m) k2 = INVALID;
    else if (k3 == m) k3 = INVALID;
    if (lane == 0) sel[q * KNN + it] = (uint32_t)(m & 0x3FFFull);
  }
}

// ---------------------------------------------------------------------------
// K3: pooled_bf16[q][c] = max over 32 selected rows of feats_bf16.
// RNE fp32->bf16 is monotone, so max(converted) == converted(max): exactly
// the bf16 the MFMA needs. block = 256 (4 queries x 64 lanes).
// ---------------------------------------------------------------------------
__global__ __launch_bounds__(256) void k_pool(const uint32_t* __restrict__ sel,
                                              const uint16_t* __restrict__ featsb,
                                              uint16_t* __restrict__ pooledb) {
  const int t = threadIdx.x;
  const int q = blockIdx.x * 4 + (t >> 6);
  const int lane = t & 63;
  const uint32_t* sq = sel + q * KNN;
  float m0 = -3.0e38f, m1 = -3.0e38f, m2 = -3.0e38f, m3 = -3.0e38f;
  #pragma unroll 8
  for (int k = 0; k < KNN; ++k) {
    const uint32_t idx = sq[k];
    const uint2 v = *(const uint2*)(featsb + (size_t)idx * CFEAT + lane * 4);
    m0 = fmaxf(m0, __uint_as_float(v.x << 16));
    m1 = fmaxf(m1, __uint_as_float(v.x & 0xffff0000u));
    m2 = fmaxf(m2, __uint_as_float(v.y << 16));
    m3 = fmaxf(m3, __uint_as_float(v.y & 0xffff0000u));
  }
  const uint32_t lo = (__float_as_uint(m0) >> 16) | (__float_as_uint(m1) & 0xffff0000u);
  const uint32_t hi = (__float_as_uint(m2) >> 16) | (__float_as_uint(m3) & 0xffff0000u);
  ((uint2*)pooledb)[(size_t)q * 64 + lane] = make_uint2(lo, hi);
}

// ---------------------------------------------------------------------------
// K4: h = pooled @ W^T + b ; LayerNorm ; ReLU -> fp32 out.
// M-tile 64, N = 256, K = 256 in 8 steps of 32; wave w owns N-slice
// [64w,64w+64) as 4x4 mfma_f32_16x16x32_bf16 tiles.
// A layout: A[m=lane&15][k=quad*8+j]; B[k=quad*8+j][n=lane&15] = W[n][k];
// D: col=lane&15, row=quad*4+reg (m89-verified).
// ---------------------------------------------------------------------------
__global__ __launch_bounds__(256) void k_gemm_ln(const uint16_t* __restrict__ pooledb,
                                                 const uint16_t* __restrict__ Wb,
                                                 const float* __restrict__ bias,
                                                 const float* __restrict__ gamma,
                                                 const float* __restrict__ beta,
                                                 float* __restrict__ out) {
  __shared__ uint16_t As[64 * 264];
  __shared__ uint16_t Bs[256 * 40];
  __shared__ float red1[4][64];
  __shared__ float red2[4][64];
  __shared__ float mu_s[64];
  __shared__ float rs_s[64];
  const int t = threadIdx.x;
  const int wave = t >> 6;
  const int lane = t & 63;
  const int quad = lane >> 4;
  const int l15 = lane & 15;
  const int m0 = blockIdx.x * 64;
  {
    const int m = t >> 2, qtr = t & 3;
    const uint4* src = (const uint4*)(pooledb + (size_t)(m0 + m) * 256 + qtr * 64);
    uint4* dst = (uint4*)(As + m * 264 + qtr * 64);
    #pragma unroll
    for (int i = 0; i < 8; ++i) dst[i] = src[i];
  }
  floatx4 acc[4][4];
  #pragma unroll
  for (int mi = 0; mi < 4; ++mi)
    #pragma unroll
    for (int ni = 0; ni < 4; ++ni)
      acc[mi][ni] = (floatx4){0.f, 0.f, 0.f, 0.f};

  for (int step = 0; step < 8; ++step) {
    __syncthreads();
    {
      const uint4* src = (const uint4*)(Wb + (size_t)t * 256 + step * 32);
      uint4* dst = (uint4*)(Bs + t * 40);
      #pragma unroll
      for (int i = 0; i < 4; ++i) dst[i] = src[i];
    }
    __syncthreads();
    short8 a[4], b[4];
    #pragma unroll
    for (int mi = 0; mi < 4; ++mi)
      a[mi] = *(const short8*)(As + (mi * 16 + l15) * 264 + step * 32 + quad * 8);
    #pragma unroll
    for (int ni = 0; ni < 4; ++ni)
      b[ni] = *(const short8*)(Bs + (wave * 64 + ni * 16 + l15) * 40 + quad * 8);
    #pragma unroll
    for (int mi = 0; mi < 4; ++mi)
      #pragma unroll
      for (int ni = 0; ni < 4; ++ni)
        acc[mi][ni] = __builtin_amdgcn_mfma_f32_16x16x32_bf16(a[mi], b[ni], acc[mi][ni], 0, 0, 0);
  }

  float bcol[4], gcol[4], zcol[4];
  #pragma unroll
  for (int ni = 0; ni < 4; ++ni) {
    const int col = wave * 64 + ni * 16 + l15;
    bcol[ni] = bias[col];
    gcol[ni] = gamma[col];
    zcol[ni] = beta[col];
  }
  #pragma unroll
  for (int mi = 0; mi < 4; ++mi)
    #pragma unroll
    for (int ni = 0; ni < 4; ++ni)
      #pragma unroll
      for (int r = 0; r < 4; ++r)
        acc[mi][ni][r] += bcol[ni];
  #pragma unroll
  for (int mi = 0; mi < 4; ++mi) {
    #pragma unroll
    for (int r = 0; r < 4; ++r) {
      const float v0 = acc[mi][0][r], v1 = acc[mi][1][r], v2 = acc[mi][2][r], v3 = acc[mi][3][r];
      float s1 = v0 + v1 + v2 + v3;
      float s2 = v0 * v0 + v1 * v1 + v2 * v2 + v3 * v3;
      #pragma unroll
      for (int off = 1; off < 16; off <<= 1) {
        s1 += __shfl_xor(s1, off, 64);
        s2 += __shfl_xor(s2, off, 64);
      }
      if (l15 == 0) {
        const int row = mi * 16 + quad * 4 + r;
        red1[wave][row] = s1;
        red2[wave][row] = s2;
      }
    }
  }
  __syncthreads();
  if (t < 64) {
    const float s1 = red1[0][t] + red1[1][t] + red1[2][t] + red1[3][t];
    const float s2 = red2[0][t] + red2[1][t] + red2[2][t] + red2[3][t];
    const float mu = s1 * (1.0f / 256.0f);
    const float var = s2 * (1.0f / 256.0f) - mu * mu;
    mu_s[t] = mu;
    rs_s[t] = 1.0f / sqrtf(var + 1e-5f);
  }
  __syncthreads();
  #pragma unroll
  for (int mi = 0; mi < 4; ++mi) {
    #pragma unroll
    for (int r = 0; r < 4; ++r) {
      const int row = mi * 16 + quad * 4 + r;
      const float mu = mu_s[row], rs = rs_s[row];
      #pragma unroll
      for (int ni = 0; ni < 4; ++ni) {
        float y = (acc[mi][ni][r] - mu) * rs * gcol[ni] + zcol[ni];
        out[(size_t)(m0 + row) * 256 + wave * 64 + ni * 16 + l15] = fmaxf(y, 0.0f);
      }
    }
  }
}

// ---------------------------------------------------------------------------
// ws: [cnt 64K][sel 2M][featsb 8M][Wb 128K][pooledb 8M][pairs 16384*cap*8]
// ---------------------------------------------------------------------------
extern "C" void kernel_launch(void* const* d_in, const int* in_sizes, int n_in,
                              void* d_out, int out_size, void* d_ws, size_t ws_size,
                              hipStream_t stream) {
  (void)in_sizes; (void)n_in; (void)out_size;
  const float* pts   = (const float*)d_in[0];
  // d_in[1] = src_masks (all True) -- unused
  const float* feats = (const float*)d_in[2];
  const float* Wm    = (const float*)d_in[3];
  const float* bias  = (const float*)d_in[4];
  const float* gamma = (const float*)d_in[5];
  const float* beta  = (const float*)d_in[6];
  float* out = (float*)d_out;

  uint8_t* ws = (uint8_t*)d_ws;
  uint32_t* cnt     = (uint32_t*)ws;                       // 65536 B
  uint32_t* sel     = (uint32_t*)(ws + 65536);             // 2 MB
  uint16_t* featsb  = (uint16_t*)(ws + 2162688);           // 8 MB
  uint16_t* Wb      = (uint16_t*)(ws + 10551296);          // 128 KB
  uint16_t* pooledb = (uint16_t*)(ws + 10682368);          // 8 MB
  uint64_t* pairs   = (uint64_t*)(ws + 19070976);
  const size_t fixed = 19070976;
  size_t avail = (ws_size > fixed) ? ws_size - fixed : 0;
  int cap = (int)(avail / ((size_t)NPTS * 8));
  if (cap > 256) cap = 256;   // max neighbor count well below 256 for this data
  if (cap < 33) cap = 33;     // degenerate-ws best effort

  (void)hipMemsetAsync(cnt, 0, NPTS * sizeof(uint32_t), stream);
  k_cvt<<<4096, 256, 0, stream>>>(feats, featsb, NPTS * CFEAT / 4);
  k_cvt<<<64, 256, 0, stream>>>(Wm, Wb, CFEAT * CFEAT / 4);
  k_filter<<<dim3(16, 32), 256, 0, stream>>>(pts, cnt, pairs, cap);
  k_select<<<NPTS / 4, 256, 0, stream>>>(cnt, pairs, sel, cap);
  k_pool<<<NPTS / 4, 256, 0, stream>>>(sel, featsb, pooledb);
  k_gemm_ln<<<NPTS / 64, 256, 0, stream>>>(pooledb, Wb, bias, gamma, beta, out);
}

// Round 4
// 241.425 us; speedup vs baseline: 1.8384x; 1.8384x over previous
//
#include <hip/hip_runtime.h>
#include <stdint.h>

#define NPTS 16384
#define CFEAT 256
#define KNN 32
#define RR_HI 0.0900101f  // fp32 prefilter band: 0.09 + 1e-5 (fp32 d2 err <= ~4.4e-7)
#define NC 34             // cells per dim
#define NCELLS (NC * NC * NC)
#define INVW 3.3332222f   // 1/0.3000100: cell width > 0.3 so |dx|<=0.3 -> cell delta <= 1

typedef __attribute__((ext_vector_type(8))) short short8;
typedef __attribute__((ext_vector_type(4))) float floatx4;

__device__ __forceinline__ uint32_t f2bf(uint32_t u) {  // RNE fp32->bf16 (finite inputs)
  return (u + 0x7fffu + ((u >> 16) & 1u)) >> 16;
}
__device__ __forceinline__ int cell1d(float x) {
  int c = (int)floorf((x + 5.1f) * INVW);
  return min(max(c, 0), NC - 1);
}

// ---------------------------------------------------------------------------
// K0: fp32 -> bf16 conversion (feats, W). 4 floats/thread.
// ---------------------------------------------------------------------------
__global__ __launch_bounds__(256) void k_cvt(const float* __restrict__ src,
                                             uint16_t* __restrict__ dst, int n4) {
  int i = blockIdx.x * 256 + threadIdx.x;
  if (i >= n4) return;
  uint4 u = ((const uint4*)src)[i];
  uint32_t lo = f2bf(u.x) | (f2bf(u.y) << 16);
  uint32_t hi = f2bf(u.z) | (f2bf(u.w) << 16);
  ((uint2*)dst)[i] = make_uint2(lo, hi);
}

// ---------------------------------------------------------------------------
// Ka: per-cell histogram. thread per point.
// ---------------------------------------------------------------------------
__global__ __launch_bounds__(256) void k_hist(const float* __restrict__ pts,
                                              uint32_t* __restrict__ cellcnt) {
  const int i = blockIdx.x * 256 + threadIdx.x;
  const int cx = cell1d(pts[3 * i]), cy = cell1d(pts[3 * i + 1]), cz = cell1d(pts[3 * i + 2]);
  atomicAdd(&cellcnt[(cz * NC + cy) * NC + cx], 1u);
}

// ---------------------------------------------------------------------------
// Kb: exclusive scan of cellcnt -> cellstart[0..NCELLS]. Single block 1024,
// wave-shfl inclusive scan + cross-wave LDS combine (2 syncs per 1024-chunk).
// ---------------------------------------------------------------------------
__global__ __launch_bounds__(1024) void k_scan(const uint32_t* __restrict__ hist,
                                               uint32_t* __restrict__ start, int n) {
  __shared__ uint32_t wsum[16];
  __shared__ uint32_t carry;
  const int t = threadIdx.x, wv = t >> 6, ln = t & 63;
  if (t == 0) carry = 0;
  __syncthreads();
  for (int base = 0; base < n; base += 1024) {
    const int i = base + t;
    const uint32_t v = (i < n) ? hist[i] : 0;
    uint32_t s = v;
    #pragma unroll
    for (int off = 1; off < 64; off <<= 1) {
      uint32_t o = __shfl_up(s, off, 64);
      if (ln >= off) s += o;
    }
    if (ln == 63) wsum[wv] = s;
    const uint32_t cbase = carry;
    __syncthreads();
    uint32_t woff = 0;
    for (int w = 0; w < wv; ++w) woff += wsum[w];
    if (i < n) start[i] = cbase + woff + s - v;
    __syncthreads();
    if (t == 1023) carry = cbase + woff + s;
    __syncthreads();
  }
  if (threadIdx.x == 0) start[n] = carry;
}

// ---------------------------------------------------------------------------
// Kc: scatter points into cell-sorted order. sortedpts[pos] = (x,y,z,idx bits);
// sortedq[pos] = idx (the spatially-sorted query order for k_pool locality).
// ---------------------------------------------------------------------------
__global__ __launch_bounds__(256) void k_scatter(const float* __restrict__ pts,
                                                 const uint32_t* __restrict__ cellstart,
                                                 uint32_t* __restrict__ cellptr,
                                                 uint32_t* __restrict__ sortedq,
                                                 float4* __restrict__ sortedpts) {
  const int i = blockIdx.x * 256 + threadIdx.x;
  const float x = pts[3 * i], y = pts[3 * i + 1], z = pts[3 * i + 2];
  const int c = (cell1d(z) * NC + cell1d(y)) * NC + cell1d(x);
  const uint32_t pos = cellstart[c] + atomicAdd(&cellptr[c], 1u);
  sortedq[pos] = (uint32_t)i;
  sortedpts[pos] = make_float4(x, y, z, __uint_as_float((uint32_t)i));
}

// ---------------------------------------------------------------------------
// K1: cell-list ball query, one wave per query, zero atomics.
// 9 (dz,dy) neighbor rows, each a contiguous x-run in sortedpts.
// fp32 prefilter band; fp64 exact d2 refine (matches np float64 ordering).
// Append via ballot-compaction; cnt[q] written once by lane 0.
// Key = (fp64 d2 bits & ~0x3FFF) | idx  -> (d2, idx) lexicographic order.
// ---------------------------------------------------------------------------
__global__ __launch_bounds__(256) void k_filter2(const float* __restrict__ pts,
                                                 const uint32_t* __restrict__ cellstart,
                                                 const float4* __restrict__ sortedpts,
                                                 uint32_t* __restrict__ cnt,
                                                 uint64_t* __restrict__ pairs,
                                                 int cap) {
  const int t = threadIdx.x;
  const int q = blockIdx.x * 4 + (t >> 6);
  const int lane = t & 63;
  const float qx = pts[3 * q], qy = pts[3 * q + 1], qz = pts[3 * q + 2];
  const int icx = cell1d(qx), icy = cell1d(qy), icz = cell1d(qz);
  const int x0 = max(icx - 1, 0), x1 = min(icx + 1, NC - 1);
  uint32_t c_run = 0;
  uint64_t* pq = pairs + (size_t)q * cap;
  #pragma unroll
  for (int dz = -1; dz <= 1; ++dz) {
    const int cz = icz + dz;
    if (cz < 0 || cz >= NC) continue;
    #pragma unroll
    for (int dy = -1; dy <= 1; ++dy) {
      const int cy = icy + dy;
      if (cy < 0 || cy >= NC) continue;
      const int rb = (cz * NC + cy) * NC;
      const int s = (int)cellstart[rb + x0];
      const int e = (int)cellstart[rb + x1 + 1];
      for (int base = s; base < e; base += 64) {
        const int i = base + lane;
        const int ii = (i < e) ? i : (e - 1);
        const float4 p = sortedpts[ii];
        const float dxf = qx - p.x, dyf = qy - p.y, dzf = qz - p.z;
        const float d2 = __fmaf_rn(dxf, dxf, __fmaf_rn(dyf, dyf, __fmul_rn(dzf, dzf)));
        bool pass = (i < e) && (d2 <= RR_HI);
        uint64_t key = 0;
        if (pass) {
          const double ddx = (double)qx - (double)p.x;
          const double ddy = (double)qy - (double)p.y;
          const double ddz = (double)qz - (double)p.z;
          const double dd2 = fma(ddx, ddx, fma(ddy, ddy, ddz * ddz));
          pass = (dd2 <= 0.3 * 0.3);  // exact double threshold, as numpy
          key = ((uint64_t)__double_as_longlong(dd2) & ~0x3FFFull) |
                (uint64_t)__float_as_uint(p.w);
        }
        const uint64_t mask = __ballot(pass);
        if (pass) {
          const uint32_t pos = c_run + (uint32_t)__popcll(mask & ((1ull << lane) - 1ull));
          if ((int)pos < cap) pq[pos] = key;
        }
        c_run += (uint32_t)__popcll(mask);
      }
    }
  }
  if (lane == 0) cnt[q] = c_run;
}

// ---------------------------------------------------------------------------
// K2: per query, final 32 indices.
// c <= 32: all in-radius (order-invariant under max-pool) + 0-padding.
// c  > 32: 32 smallest (d2, idx) keys via wave-wide repeated argmin.
// ---------------------------------------------------------------------------
__global__ __launch_bounds__(256) void k_select(const uint32_t* __restrict__ cnt,
                                                const uint64_t* __restrict__ pairs,
                                                uint32_t* __restrict__ sel,
                                                int cap) {
  const int t = threadIdx.x;
  const int q = blockIdx.x * 4 + (t >> 6);
  const int lane = t & 63;
  int c = (int)cnt[q];
  if (c > cap) c = cap;
  const uint64_t* pp = pairs + (size_t)q * cap;
  if (c <= KNN) {
    if (lane < KNN) sel[q * KNN + lane] = (lane < c) ? (uint32_t)(pp[lane] & 0x3FFFull) : 0u;
    return;
  }
  const uint64_t INVALID = ~0ull;
  uint64_t k0 = (lane < c) ? pp[lane] : INVALID;
  uint64_t k1 = (lane + 64 < c) ? pp[lane + 64] : INVALID;
  uint64_t k2 = (lane + 128 < c) ? pp[lane + 128] : INVALID;
  uint64_t k3 = (lane + 192 < c) ? pp[lane + 192] : INVALID;
  for (int it = 0; it < KNN; ++it) {
    uint64_t a = k0 < k1 ? k0 : k1;
    uint64_t b = k2 < k3 ? k2 : k3;
    uint64_t m = a < b ? a : b;
    #pragma unroll
    for (int off = 1; off < 64; off <<= 1) {
      uint64_t o = (uint64_t)__shfl_xor((unsigned long long)m, off, 64);
      m = o < m ? o : m;
    }
    if (k0 == m) k0 = INVALID;
    else if (k1 == m) k1 = INVALID;
    else if (k2 == m) k2 = INVALID;
    else if (k3 == m) k3 = INVALID;
    if (lane == 0) sel[q * KNN + it] = (uint32_t)(m & 0x3FFFull);
  }
}

// ---------------------------------------------------------------------------
// K3: pooled_bf16[q][c] = max over 32 selected rows of feats_bf16.
// Processes queries in spatially-sorted order (sortedq) so adjacent waves
// gather overlapping featsb rows -> L1/L2 hits. Output indexed by original q.
// ---------------------------------------------------------------------------
__global__ __launch_bounds__(256) void k_pool(const uint32_t* __restrict__ sortedq,
                                              const uint32_t* __restrict__ sel,
                                              const uint16_t* __restrict__ featsb,
                                              uint16_t* __restrict__ pooledb) {
  const int t = threadIdx.x;
  const int q = (int)sortedq[blockIdx.x * 4 + (t >> 6)];
  const int lane = t & 63;
  const uint32_t* sq = sel + q * KNN;
  float m0 = -3.0e38f, m1 = -3.0e38f, m2 = -3.0e38f, m3 = -3.0e38f;
  #pragma unroll 8
  for (int k = 0; k < KNN; ++k) {
    const uint32_t idx = sq[k];
    const uint2 v = *(const uint2*)(featsb + (size_t)idx * CFEAT + lane * 4);
    m0 = fmaxf(m0, __uint_as_float(v.x << 16));
    m1 = fmaxf(m1, __uint_as_float(v.x & 0xffff0000u));
    m2 = fmaxf(m2, __uint_as_float(v.y << 16));
    m3 = fmaxf(m3, __uint_as_float(v.y & 0xffff0000u));
  }
  const uint32_t lo = (__float_as_uint(m0) >> 16) | (__float_as_uint(m1) & 0xffff0000u);
  const uint32_t hi = (__float_as_uint(m2) >> 16) | (__float_as_uint(m3) & 0xffff0000u);
  ((uint2*)pooledb)[(size_t)q * 64 + lane] = make_uint2(lo, hi);
}

// ---------------------------------------------------------------------------
// K4: h = pooled @ W^T + b ; LayerNorm ; ReLU -> fp32 out.
// M-tile 64, N = 256, K = 256 in 8 steps of 32; wave w owns N-slice
// [64w,64w+64) as 4x4 mfma_f32_16x16x32_bf16 tiles.
// ---------------------------------------------------------------------------
__global__ __launch_bounds__(256) void k_gemm_ln(const uint16_t* __restrict__ pooledb,
                                                 const uint16_t* __restrict__ Wb,
                                                 const float* __restrict__ bias,
                                                 const float* __restrict__ gamma,
                                                 const float* __restrict__ beta,
                                                 float* __restrict__ out) {
  __shared__ uint16_t As[64 * 264];
  __shared__ uint16_t Bs[256 * 40];
  __shared__ float red1[4][64];
  __shared__ float red2[4][64];
  __shared__ float mu_s[64];
  __shared__ float rs_s[64];
  const int t = threadIdx.x;
  const int wave = t >> 6;
  const int lane = t & 63;
  const int quad = lane >> 4;
  const int l15 = lane & 15;
  const int m0 = blockIdx.x * 64;
  {
    const int m = t >> 2, qtr = t & 3;
    const uint4* src = (const uint4*)(pooledb + (size_t)(m0 + m) * 256 + qtr * 64);
    uint4* dst = (uint4*)(As + m * 264 + qtr * 64);
    #pragma unroll
    for (int i = 0; i < 8; ++i) dst[i] = src[i];
  }
  floatx4 acc[4][4];
  #pragma unroll
  for (int mi = 0; mi < 4; ++mi)
    #pragma unroll
    for (int ni = 0; ni < 4; ++ni)
      acc[mi][ni] = (floatx4){0.f, 0.f, 0.f, 0.f};

  for (int step = 0; step < 8; ++step) {
    __syncthreads();
    {
      const uint4* src = (const uint4*)(Wb + (size_t)t * 256 + step * 32);
      uint4* dst = (uint4*)(Bs + t * 40);
      #pragma unroll
      for (int i = 0; i < 4; ++i) dst[i] = src[i];
    }
    __syncthreads();
    short8 a[4], b[4];
    #pragma unroll
    for (int mi = 0; mi < 4; ++mi)
      a[mi] = *(const short8*)(As + (mi * 16 + l15) * 264 + step * 32 + quad * 8);
    #pragma unroll
    for (int ni = 0; ni < 4; ++ni)
      b[ni] = *(const short8*)(Bs + (wave * 64 + ni * 16 + l15) * 40 + quad * 8);
    #pragma unroll
    for (int mi = 0; mi < 4; ++mi)
      #pragma unroll
      for (int ni = 0; ni < 4; ++ni)
        acc[mi][ni] = __builtin_amdgcn_mfma_f32_16x16x32_bf16(a[mi], b[ni], acc[mi][ni], 0, 0, 0);
  }

  float bcol[4], gcol[4], zcol[4];
  #pragma unroll
  for (int ni = 0; ni < 4; ++ni) {
    const int col = wave * 64 + ni * 16 + l15;
    bcol[ni] = bias[col];
    gcol[ni] = gamma[col];
    zcol[ni] = beta[col];
  }
  #pragma unroll
  for (int mi = 0; mi < 4; ++mi)
    #pragma unroll
    for (int ni = 0; ni < 4; ++ni)
      #pragma unroll
      for (int r = 0; r < 4; ++r)
        acc[mi][ni][r] += bcol[ni];
  #pragma unroll
  for (int mi = 0; mi < 4; ++mi) {
    #pragma unroll
    for (int r = 0; r < 4; ++r) {
      const float v0 = acc[mi][0][r], v1 = acc[mi][1][r], v2 = acc[mi][2][r], v3 = acc[mi][3][r];
      float s1 = v0 + v1 + v2 + v3;
      float s2 = v0 * v0 + v1 * v1 + v2 * v2 + v3 * v3;
      #pragma unroll
      for (int off = 1; off < 16; off <<= 1) {
        s1 += __shfl_xor(s1, off, 64);
        s2 += __shfl_xor(s2, off, 64);
      }
      if (l15 == 0) {
        const int row = mi * 16 + quad * 4 + r;
        red1[wave][row] = s1;
        red2[wave][row] = s2;
      }
    }
  }
  __syncthreads();
  if (t < 64) {
    const float s1 = red1[0][t] + red1[1][t] + red1[2][t] + red1[3][t];
    const float s2 = red2[0][t] + red2[1][t] + red2[2][t] + red2[3][t];
    const float mu = s1 * (1.0f / 256.0f);
    const float var = s2 * (1.0f / 256.0f) - mu * mu;
    mu_s[t] = mu;
    rs_s[t] = 1.0f / sqrtf(var + 1e-5f);
  }
  __syncthreads();
  #pragma unroll
  for (int mi = 0; mi < 4; ++mi) {
    #pragma unroll
    for (int r = 0; r < 4; ++r) {
      const int row = mi * 16 + quad * 4 + r;
      const float mu = mu_s[row], rs = rs_s[row];
      #pragma unroll
      for (int ni = 0; ni < 4; ++ni) {
        float y = (acc[mi][ni][r] - mu) * rs * gcol[ni] + zcol[ni];
        out[(size_t)(m0 + row) * 256 + wave * 64 + ni * 16 + l15] = fmaxf(y, 0.0f);
      }
    }
  }
}

// ---------------------------------------------------------------------------
// ws: [cnt 64K][sel 2M][featsb 8M][Wb 128K][pooledb 8M][cellcnt 154K]
//     [cellptr 154K][cellstart 154K][sortedq 64K][sortedpts 256K][pairs ...]
// ---------------------------------------------------------------------------
extern "C" void kernel_launch(void* const* d_in, const int* in_sizes, int n_in,
                              void* d_out, int out_size, void* d_ws, size_t ws_size,
                              hipStream_t stream) {
  (void)in_sizes; (void)n_in; (void)out_size;
  const float* pts   = (const float*)d_in[0];
  // d_in[1] = src_masks (all True) -- unused
  const float* feats = (const float*)d_in[2];
  const float* Wm    = (const float*)d_in[3];
  const float* bias  = (const float*)d_in[4];
  const float* gamma = (const float*)d_in[5];
  const float* beta  = (const float*)d_in[6];
  float* out = (float*)d_out;

  uint8_t* ws = (uint8_t*)d_ws;
  uint32_t* cnt       = (uint32_t*)ws;                      // @0       64 KB
  uint32_t* sel       = (uint32_t*)(ws + 65536);            // @64K     2 MB
  uint16_t* featsb    = (uint16_t*)(ws + 2162688);          // @2.06M   8 MB
  uint16_t* Wb        = (uint16_t*)(ws + 10551296);         // @10.06M  128 KB
  uint16_t* pooledb   = (uint16_t*)(ws + 10682368);         // @10.19M  8 MB
  uint32_t* cellcnt   = (uint32_t*)(ws + 19070976);         // 157216 B
  uint32_t* cellptr   = (uint32_t*)(ws + 19228192);         // 157216 B
  uint32_t* cellstart = (uint32_t*)(ws + 19385408);         // 157220 B (pad 157440)
  uint32_t* sortedq   = (uint32_t*)(ws + 19542848);         // 64 KB
  float4*   sortedpts = (float4*)(ws + 19608384);           // 256 KB
  uint64_t* pairs     = (uint64_t*)(ws + 19870528);
  const size_t fixed = 19870528;
  size_t avail = (ws_size > fixed) ? ws_size - fixed : 0;
  int cap = (int)(avail / ((size_t)NPTS * 8));
  if (cap > 256) cap = 256;   // max neighbor count well below 256 for this data
  if (cap < 33) cap = 33;     // degenerate-ws best effort

  (void)hipMemsetAsync(cellcnt, 0, 2 * 157216, stream);  // cellcnt + cellptr
  k_cvt<<<4096, 256, 0, stream>>>(feats, featsb, NPTS * CFEAT / 4);
  k_cvt<<<64, 256, 0, stream>>>(Wm, Wb, CFEAT * CFEAT / 4);
  k_hist<<<NPTS / 256, 256, 0, stream>>>(pts, cellcnt);
  k_scan<<<1, 1024, 0, stream>>>(cellcnt, cellstart, NCELLS);
  k_scatter<<<NPTS / 256, 256, 0, stream>>>(pts, cellstart, cellptr, sortedq, sortedpts);
  k_filter2<<<NPTS / 4, 256, 0, stream>>>(pts, cellstart, sortedpts, cnt, pairs, cap);
  k_select<<<NPTS / 4, 256, 0, stream>>>(cnt, pairs, sel, cap);
  k_pool<<<NPTS / 4, 256, 0, stream>>>(sortedq, sel, featsb, pooledb);
  k_gemm_ln<<<NPTS / 64, 256, 0, stream>>>(pooledb, Wb, bias, gamma, beta, out);
}

// Round 5
// 155.763 us; speedup vs baseline: 2.8494x; 1.5500x over previous
//
#include <hip/hip_runtime.h>
#include <stdint.h>

#define NPTS 16384
#define CFEAT 256
#define KNN 32
#define RR_HI 0.0900101f  // fp32 prefilter band: 0.09 + 1e-5 (fp32 d2 err <= ~4.4e-7)
#define NC 34             // cells per dim
#define NCELLS (NC * NC * NC)
#define INVW 3.3332222f   // 1/0.3000100: cell width > 0.3 so |dx|<=0.3 -> cell delta <= 1
#define NBUCK 128

typedef __attribute__((ext_vector_type(8))) short short8;
typedef __attribute__((ext_vector_type(4))) float floatx4;

__device__ __forceinline__ uint32_t f2bf(uint32_t u) {  // RNE fp32->bf16 (finite inputs)
  return (u + 0x7fffu + ((u >> 16) & 1u)) >> 16;
}
__device__ __forceinline__ int cell1d(float x) {
  int c = (int)floorf((x + 5.1f) * INVW);
  return min(max(c, 0), NC - 1);
}

// ---------------------------------------------------------------------------
// K0: fp32 -> bf16 conversion (feats, W). 4 floats/thread.
// ---------------------------------------------------------------------------
__global__ __launch_bounds__(256) void k_cvt(const float* __restrict__ src,
                                             uint16_t* __restrict__ dst, int n4) {
  int i = blockIdx.x * 256 + threadIdx.x;
  if (i >= n4) return;
  uint4 u = ((const uint4*)src)[i];
  uint32_t lo = f2bf(u.x) | (f2bf(u.y) << 16);
  uint32_t hi = f2bf(u.z) | (f2bf(u.w) << 16);
  ((uint2*)dst)[i] = make_uint2(lo, hi);
}

// ---------------------------------------------------------------------------
// Ka: per-cell histogram. thread per point.
// ---------------------------------------------------------------------------
__global__ __launch_bounds__(256) void k_hist(const float* __restrict__ pts,
                                              uint32_t* __restrict__ cellcnt) {
  const int i = blockIdx.x * 256 + threadIdx.x;
  const int cx = cell1d(pts[3 * i]), cy = cell1d(pts[3 * i + 1]), cz = cell1d(pts[3 * i + 2]);
  atomicAdd(&cellcnt[(cz * NC + cy) * NC + cx], 1u);
}

// ---------------------------------------------------------------------------
// Kb: exclusive scan of cellcnt -> cellstart[0..NCELLS]. Single block 1024,
// 4 elements/thread (uint4), wave-shfl scan + cross-wave LDS combine.
// NCELLS = 39304 is divisible by 4 -> 9826 quads, 10 chunks.
// ---------------------------------------------------------------------------
__global__ __launch_bounds__(1024) void k_scan(const uint32_t* __restrict__ hist,
                                               uint32_t* __restrict__ start, int n) {
  __shared__ uint32_t wsum[16];
  __shared__ uint32_t carry;
  const int t = threadIdx.x, wv = t >> 6, ln = t & 63;
  if (t == 0) carry = 0;
  __syncthreads();
  const int nq = n >> 2;
  for (int qb = 0; qb < nq; qb += 1024) {
    const int i4 = qb + t;
    uint4 v = make_uint4(0, 0, 0, 0);
    if (i4 < nq) v = ((const uint4*)hist)[i4];
    const uint32_t tot = v.x + v.y + v.z + v.w;
    uint32_t s = tot;
    #pragma unroll
    for (int off = 1; off < 64; off <<= 1) {
      uint32_t o = __shfl_up(s, off, 64);
      if (ln >= off) s += o;
    }
    if (ln == 63) wsum[wv] = s;
    const uint32_t cbase = carry;
    __syncthreads();
    uint32_t woff = 0;
    for (int w = 0; w < wv; ++w) woff += wsum[w];
    if (i4 < nq) {
      const uint32_t e = cbase + woff + s - tot;
      ((uint4*)start)[i4] = make_uint4(e, e + v.x, e + v.x + v.y, e + v.x + v.y + v.z);
    }
    __syncthreads();
    if (t == 1023) carry = cbase + woff + s;
    __syncthreads();
  }
  if (t == 0) start[n] = carry;
}

// ---------------------------------------------------------------------------
// Kc: scatter points into cell-sorted order. sortedpts[pos] = (x,y,z,idx bits);
// sortedq[pos] = idx (spatially-sorted query order).
// ---------------------------------------------------------------------------
__global__ __launch_bounds__(256) void k_scatter(const float* __restrict__ pts,
                                                 const uint32_t* __restrict__ cellstart,
                                                 uint32_t* __restrict__ cellptr,
                                                 uint32_t* __restrict__ sortedq,
                                                 float4* __restrict__ sortedpts) {
  const int i = blockIdx.x * 256 + threadIdx.x;
  const float x = pts[3 * i], y = pts[3 * i + 1], z = pts[3 * i + 2];
  const int c = (cell1d(z) * NC + cell1d(y)) * NC + cell1d(x);
  const uint32_t pos = cellstart[c] + atomicAdd(&cellptr[c], 1u);
  sortedq[pos] = (uint32_t)i;
  sortedpts[pos] = make_float4(x, y, z, __uint_as_float((uint32_t)i));
}

// ---------------------------------------------------------------------------
// K1 (fused filter+select+pool): one wave per query, queries in sorted order.
// Phase F: cell-list ball query -> keys in LDS (ballot-compaction, 0 atomics).
//   Key = (fp64 d2 bits & ~0x3FFF) | idx  -> (d2, idx) lexicographic.
// Phase S: set-of-32-smallest via 128-bucket d2 histogram rank-select:
//   buckets < b* are winners (ballot-compact), boundary bucket b* via
//   (32 - m) wave-argmins (expected ~1-3 iterations).
// Phase P: max-pool the 32 selected feature rows (bf16), write pooledb[q].
// ---------------------------------------------------------------------------
__global__ __launch_bounds__(256) void k_fsp(const uint32_t* __restrict__ sortedq,
                                             const uint32_t* __restrict__ cellstart,
                                             const float4* __restrict__ sortedpts,
                                             const uint16_t* __restrict__ featsb,
                                             uint16_t* __restrict__ pooledb) {
  __shared__ uint64_t keys[4][256];
  __shared__ uint32_t hist[4][NBUCK];
  __shared__ uint32_t sids[4][KNN];
  const int t = threadIdx.x;
  const int w = t >> 6;
  const int lane = t & 63;
  const uint64_t ltmask = (1ull << lane) - 1ull;
  const int q = (int)sortedq[blockIdx.x * 4 + w];
  const float qx = sortedpts[blockIdx.x * 4 + w].x;  // same point, sorted copy
  const float qy = sortedpts[blockIdx.x * 4 + w].y;
  const float qz = sortedpts[blockIdx.x * 4 + w].z;
  const int icx = cell1d(qx), icy = cell1d(qy), icz = cell1d(qz);
  const int x0 = max(icx - 1, 0), x1 = min(icx + 1, NC - 1);
  uint32_t c_run = 0;
  // ---- Phase F ----
  #pragma unroll
  for (int dz = -1; dz <= 1; ++dz) {
    const int cz = icz + dz;
    if (cz < 0 || cz >= NC) continue;
    #pragma unroll
    for (int dy = -1; dy <= 1; ++dy) {
      const int cy = icy + dy;
      if (cy < 0 || cy >= NC) continue;
      const int rb = (cz * NC + cy) * NC;
      const int s = (int)cellstart[rb + x0];
      const int e = (int)cellstart[rb + x1 + 1];
      for (int base = s; base < e; base += 64) {
        const int i = base + lane;
        const int ii = (i < e) ? i : (e - 1);
        const float4 p = sortedpts[ii];
        const float dxf = qx - p.x, dyf = qy - p.y, dzf = qz - p.z;
        const float d2 = __fmaf_rn(dxf, dxf, __fmaf_rn(dyf, dyf, __fmul_rn(dzf, dzf)));
        bool pass = (i < e) && (d2 <= RR_HI);
        uint64_t key = 0;
        if (pass) {
          const double ddx = (double)qx - (double)p.x;
          const double ddy = (double)qy - (double)p.y;
          const double ddz = (double)qz - (double)p.z;
          const double dd2 = fma(ddx, ddx, fma(ddy, ddy, ddz * ddz));
          pass = (dd2 <= 0.3 * 0.3);  // exact double threshold, as numpy
          key = ((uint64_t)__double_as_longlong(dd2) & ~0x3FFFull) |
                (uint64_t)__float_as_uint(p.w);
        }
        const uint64_t mask = __ballot(pass);
        if (pass) {
          const uint32_t pos = c_run + (uint32_t)__popcll(mask & ltmask);
          if (pos < 256u) keys[w][pos] = key;
        }
        c_run += (uint32_t)__popcll(mask);
      }
    }
  }
  const int c = (int)min(c_run, 256u);
  // ---- Phase S ----
  if (c <= KNN) {
    if (lane < KNN) sids[w][lane] = (lane < c) ? (uint32_t)(keys[w][lane] & 0x3FFFull) : 0u;
  } else {
    const uint64_t INVALID = ~0ull;
    uint64_t k0 = (lane < c) ? keys[w][lane] : INVALID;
    uint64_t k1 = (lane + 64 < c) ? keys[w][lane + 64] : INVALID;
    uint64_t k2 = (lane + 128 < c) ? keys[w][lane + 128] : INVALID;
    uint64_t k3 = (lane + 192 < c) ? keys[w][lane + 192] : INVALID;
    hist[w][lane] = 0;
    hist[w][lane + 64] = 0;
    int b0 = 999, b1 = 999, b2 = 999, b3 = 999;
    const float bs = 128.0f / 0.09f;
    if (k0 != INVALID) { b0 = min(NBUCK - 1, (int)((float)__longlong_as_double((long long)(k0 & ~0x3FFFull)) * bs)); atomicAdd(&hist[w][b0], 1u); }
    if (k1 != INVALID) { b1 = min(NBUCK - 1, (int)((float)__longlong_as_double((long long)(k1 & ~0x3FFFull)) * bs)); atomicAdd(&hist[w][b1], 1u); }
    if (k2 != INVALID) { b2 = min(NBUCK - 1, (int)((float)__longlong_as_double((long long)(k2 & ~0x3FFFull)) * bs)); atomicAdd(&hist[w][b2], 1u); }
    if (k3 != INVALID) { b3 = min(NBUCK - 1, (int)((float)__longlong_as_double((long long)(k3 & ~0x3FFFull)) * bs)); atomicAdd(&hist[w][b3], 1u); }
    // wave scan of bucket counts: lane owns buckets 2*lane, 2*lane+1
    const uint32_t h0 = hist[w][2 * lane], h1 = hist[w][2 * lane + 1];
    const uint32_t tot = h0 + h1;
    uint32_t s = tot;
    #pragma unroll
    for (int off = 1; off < 64; off <<= 1) {
      uint32_t o = __shfl_up(s, off, 64);
      if (lane >= off) s += o;
    }
    const uint32_t C0 = s - tot + h0;  // inclusive cum of bucket 2*lane
    const uint32_t C1 = s - tot + h0 + h1;
    const uint64_t me = __ballot(C0 >= KNN);
    const uint64_t mo = __ballot(C1 >= KNN);
    const int be = me ? 2 * (__ffsll((unsigned long long)me) - 1) : (1 << 30);
    const int bo = mo ? 2 * (__ffsll((unsigned long long)mo) - 1) + 1 : (1 << 30);
    const int bstar = min(be, bo);
    const uint32_t mval_mine = (bstar & 1) ? (C1 - h1) : (C0 - h0);
    const uint32_t m = (uint32_t)__shfl((int)mval_mine, bstar >> 1, 64);
    // winners: bucket < b*
    uint32_t wpos = 0;
    {
      bool win = (b0 < bstar);
      uint64_t bm = __ballot(win);
      if (win) sids[w][wpos + (uint32_t)__popcll(bm & ltmask)] = (uint32_t)(k0 & 0x3FFFull);
      wpos += (uint32_t)__popcll(bm);
      win = (b1 < bstar); bm = __ballot(win);
      if (win) sids[w][wpos + (uint32_t)__popcll(bm & ltmask)] = (uint32_t)(k1 & 0x3FFFull);
      wpos += (uint32_t)__popcll(bm);
      win = (b2 < bstar); bm = __ballot(win);
      if (win) sids[w][wpos + (uint32_t)__popcll(bm & ltmask)] = (uint32_t)(k2 & 0x3FFFull);
      wpos += (uint32_t)__popcll(bm);
      win = (b3 < bstar); bm = __ballot(win);
      if (win) sids[w][wpos + (uint32_t)__popcll(bm & ltmask)] = (uint32_t)(k3 & 0x3FFFull);
      wpos += (uint32_t)__popcll(bm);
    }
    // boundary bucket: (32 - m) smallest among bucket == b*
    uint64_t e0 = (b0 == bstar) ? k0 : INVALID;
    uint64_t e1 = (b1 == bstar) ? k1 : INVALID;
    uint64_t e2 = (b2 == bstar) ? k2 : INVALID;
    uint64_t e3 = (b3 == bstar) ? k3 : INVALID;
    const int need = KNN - (int)m;
    for (int it = 0; it < need; ++it) {
      uint64_t a = e0 < e1 ? e0 : e1;
      uint64_t b = e2 < e3 ? e2 : e3;
      uint64_t mn = a < b ? a : b;
      #pragma unroll
      for (int off = 1; off < 64; off <<= 1) {
        uint64_t o = (uint64_t)__shfl_xor((unsigned long long)mn, off, 64);
        mn = o < mn ? o : mn;
      }
      if (e0 == mn) e0 = INVALID;
      else if (e1 == mn) e1 = INVALID;
      else if (e2 == mn) e2 = INVALID;
      else if (e3 == mn) e3 = INVALID;
      if (lane == 0) sids[w][m + it] = (uint32_t)(mn & 0x3FFFull);
    }
  }
  // ---- Phase P ----
  float m0 = -3.0e38f, m1 = -3.0e38f, m2 = -3.0e38f, m3 = -3.0e38f;
  #pragma unroll 8
  for (int k = 0; k < KNN; ++k) {
    const uint32_t idx = sids[w][k];
    const uint2 v = *(const uint2*)(featsb + (size_t)idx * CFEAT + lane * 4);
    m0 = fmaxf(m0, __uint_as_float(v.x << 16));
    m1 = fmaxf(m1, __uint_as_float(v.x & 0xffff0000u));
    m2 = fmaxf(m2, __uint_as_float(v.y << 16));
    m3 = fmaxf(m3, __uint_as_float(v.y & 0xffff0000u));
  }
  const uint32_t lo = (__float_as_uint(m0) >> 16) | (__float_as_uint(m1) & 0xffff0000u);
  const uint32_t hi = (__float_as_uint(m2) >> 16) | (__float_as_uint(m3) & 0xffff0000u);
  ((uint2*)pooledb)[(size_t)q * 64 + lane] = make_uint2(lo, hi);
}

// ---------------------------------------------------------------------------
// K4: h = pooled @ W^T + b ; LayerNorm ; ReLU -> fp32 out.
// M-tile 64, N = 256, K = 256 in 8 steps of 32; wave w owns N-slice
// [64w,64w+64) as 4x4 mfma_f32_16x16x32_bf16 tiles.
// ---------------------------------------------------------------------------
__global__ __launch_bounds__(256) void k_gemm_ln(const uint16_t* __restrict__ pooledb,
                                                 const uint16_t* __restrict__ Wb,
                                                 const float* __restrict__ bias,
                                                 const float* __restrict__ gamma,
                                                 const float* __restrict__ beta,
                                                 float* __restrict__ out) {
  __shared__ uint16_t As[64 * 264];
  __shared__ uint16_t Bs[256 * 40];
  __shared__ float red1[4][64];
  __shared__ float red2[4][64];
  __shared__ float mu_s[64];
  __shared__ float rs_s[64];
  const int t = threadIdx.x;
  const int wave = t >> 6;
  const int lane = t & 63;
  const int quad = lane >> 4;
  const int l15 = lane & 15;
  const int m0 = blockIdx.x * 64;
  {
    const int m = t >> 2, qtr = t & 3;
    const uint4* src = (const uint4*)(pooledb + (size_t)(m0 + m) * 256 + qtr * 64);
    uint4* dst = (uint4*)(As + m * 264 + qtr * 64);
    #pragma unroll
    for (int i = 0; i < 8; ++i) dst[i] = src[i];
  }
  floatx4 acc[4][4];
  #pragma unroll
  for (int mi = 0; mi < 4; ++mi)
    #pragma unroll
    for (int ni = 0; ni < 4; ++ni)
      acc[mi][ni] = (floatx4){0.f, 0.f, 0.f, 0.f};

  for (int step = 0; step < 8; ++step) {
    __syncthreads();
    {
      const uint4* src = (const uint4*)(Wb + (size_t)t * 256 + step * 32);
      uint4* dst = (uint4*)(Bs + t * 40);
      #pragma unroll
      for (int i = 0; i < 4; ++i) dst[i] = src[i];
    }
    __syncthreads();
    short8 a[4], b[4];
    #pragma unroll
    for (int mi = 0; mi < 4; ++mi)
      a[mi] = *(const short8*)(As + (mi * 16 + l15) * 264 + step * 32 + quad * 8);
    #pragma unroll
    for (int ni = 0; ni < 4; ++ni)
      b[ni] = *(const short8*)(Bs + (wave * 64 + ni * 16 + l15) * 40 + quad * 8);
    #pragma unroll
    for (int mi = 0; mi < 4; ++mi)
      #pragma unroll
      for (int ni = 0; ni < 4; ++ni)
        acc[mi][ni] = __builtin_amdgcn_mfma_f32_16x16x32_bf16(a[mi], b[ni], acc[mi][ni], 0, 0, 0);
  }

  float bcol[4], gcol[4], zcol[4];
  #pragma unroll
  for (int ni = 0; ni < 4; ++ni) {
    const int col = wave * 64 + ni * 16 + l15;
    bcol[ni] = bias[col];
    gcol[ni] = gamma[col];
    zcol[ni] = beta[col];
  }
  #pragma unroll
  for (int mi = 0; mi < 4; ++mi)
    #pragma unroll
    for (int ni = 0; ni < 4; ++ni)
      #pragma unroll
      for (int r = 0; r < 4; ++r)
        acc[mi][ni][r] += bcol[ni];
  #pragma unroll
  for (int mi = 0; mi < 4; ++mi) {
    #pragma unroll
    for (int r = 0; r < 4; ++r) {
      const float v0 = acc[mi][0][r], v1 = acc[mi][1][r], v2 = acc[mi][2][r], v3 = acc[mi][3][r];
      float s1 = v0 + v1 + v2 + v3;
      float s2 = v0 * v0 + v1 * v1 + v2 * v2 + v3 * v3;
      #pragma unroll
      for (int off = 1; off < 16; off <<= 1) {
        s1 += __shfl_xor(s1, off, 64);
        s2 += __shfl_xor(s2, off, 64);
      }
      if (l15 == 0) {
        const int row = mi * 16 + quad * 4 + r;
        red1[wave][row] = s1;
        red2[wave][row] = s2;
      }
    }
  }
  __syncthreads();
  if (t < 64) {
    const float s1 = red1[0][t] + red1[1][t] + red1[2][t] + red1[3][t];
    const float s2 = red2[0][t] + red2[1][t] + red2[2][t] + red2[3][t];
    const float mu = s1 * (1.0f / 256.0f);
    const float var = s2 * (1.0f / 256.0f) - mu * mu;
    mu_s[t] = mu;
    rs_s[t] = 1.0f / sqrtf(var + 1e-5f);
  }
  __syncthreads();
  #pragma unroll
  for (int mi = 0; mi < 4; ++mi) {
    #pragma unroll
    for (int r = 0; r < 4; ++r) {
      const int row = mi * 16 + quad * 4 + r;
      const float mu = mu_s[row], rs = rs_s[row];
      #pragma unroll
      for (int ni = 0; ni < 4; ++ni) {
        float y = (acc[mi][ni][r] - mu) * rs * gcol[ni] + zcol[ni];
        out[(size_t)(m0 + row) * 256 + wave * 64 + ni * 16 + l15] = fmaxf(y, 0.0f);
      }
    }
  }
}

// ---------------------------------------------------------------------------
// ws: [featsb 8M][Wb 128K][pooledb 8M][cellcnt][cellptr][cellstart][sortedq]
//     [sortedpts]  (pairs/cnt/sel eliminated by fusion)
// ---------------------------------------------------------------------------
extern "C" void kernel_launch(void* const* d_in, const int* in_sizes, int n_in,
                              void* d_out, int out_size, void* d_ws, size_t ws_size,
                              hipStream_t stream) {
  (void)in_sizes; (void)n_in; (void)out_size; (void)ws_size;
  const float* pts   = (const float*)d_in[0];
  // d_in[1] = src_masks (all True) -- unused
  const float* feats = (const float*)d_in[2];
  const float* Wm    = (const float*)d_in[3];
  const float* bias  = (const float*)d_in[4];
  const float* gamma = (const float*)d_in[5];
  const float* beta  = (const float*)d_in[6];
  float* out = (float*)d_out;

  uint8_t* ws = (uint8_t*)d_ws;
  uint16_t* featsb    = (uint16_t*)ws;                      // @0        8 MB
  uint16_t* Wb        = (uint16_t*)(ws + 8388608);          // 128 KB
  uint16_t* pooledb   = (uint16_t*)(ws + 8519680);          // 8 MB
  uint32_t* cellcnt   = (uint32_t*)(ws + 16908288);         // 157440 B (NCELLS*4 pad)
  uint32_t* cellptr   = (uint32_t*)(ws + 17065728);         // 157440 B
  uint32_t* cellstart = (uint32_t*)(ws + 17223168);         // 157440 B ((NCELLS+1)*4 pad)
  uint32_t* sortedq   = (uint32_t*)(ws + 17380608);         // 64 KB
  float4*   sortedpts = (float4*)(ws + 17446144);           // 256 KB -> end 17708288

  (void)hipMemsetAsync(cellcnt, 0, 2 * 157440, stream);  // cellcnt + cellptr
  k_cvt<<<4096, 256, 0, stream>>>(feats, featsb, NPTS * CFEAT / 4);
  k_cvt<<<64, 256, 0, stream>>>(Wm, Wb, CFEAT * CFEAT / 4);
  k_hist<<<NPTS / 256, 256, 0, stream>>>(pts, cellcnt);
  k_scan<<<1, 1024, 0, stream>>>(cellcnt, cellstart, NCELLS);
  k_scatter<<<NPTS / 256, 256, 0, stream>>>(pts, cellstart, cellptr, sortedq, sortedpts);
  k_fsp<<<NPTS / 4, 256, 0, stream>>>(sortedq, cellstart, sortedpts, featsb, pooledb);
  k_gemm_ln<<<NPTS / 64, 256, 0, stream>>>(pooledb, Wb, bias, gamma, beta, out);
}

// Round 6
// 145.755 us; speedup vs baseline: 3.0450x; 1.0687x over previous
//
#include <hip/hip_runtime.h>
#include <stdint.h>

#define NPTS 16384
#define CFEAT 256
#define KNN 32
#define RR_HI 0.0900101f  // fp32 prefilter band: 0.09 + 1e-5 (fp32 d2 err <= ~4.4e-7)
#define NC 34             // cells per dim
#define NCELLS (NC * NC * NC)
#define INVW 3.3332222f   // 1/0.3000100: cell width > 0.3 so |dx|<=0.3 -> cell delta <= 1
#define NBUCK 128

typedef __attribute__((ext_vector_type(8))) short short8;
typedef __attribute__((ext_vector_type(4))) float floatx4;

__device__ __forceinline__ uint32_t f2bf(uint32_t u) {  // RNE fp32->bf16 (finite inputs)
  return (u + 0x7fffu + ((u >> 16) & 1u)) >> 16;
}
__device__ __forceinline__ int cell1d(float x) {
  int c = (int)floorf((x + 5.1f) * INVW);
  return min(max(c, 0), NC - 1);
}

// ---------------------------------------------------------------------------
// K_prep (fused): blocks [0,4096) convert feats fp32->bf16 (4 floats/thread);
// blocks [4096,4160) convert W AND build the cell histogram (16384 items each,
// exactly 64 blocks x 256 threads). cellcnt zeroed by the preceding memset.
// ---------------------------------------------------------------------------
__global__ __launch_bounds__(256) void k_prep(const float* __restrict__ feats,
                                              uint16_t* __restrict__ featsb,
                                              const float* __restrict__ Wm,
                                              uint16_t* __restrict__ Wb,
                                              const float* __restrict__ pts,
                                              uint32_t* __restrict__ cellcnt) {
  const int b = blockIdx.x, t = threadIdx.x;
  if (b < 4096) {
    const int i = b * 256 + t;  // < NPTS*CFEAT/4
    const uint4 u = ((const uint4*)feats)[i];
    const uint32_t lo = f2bf(u.x) | (f2bf(u.y) << 16);
    const uint32_t hi = f2bf(u.z) | (f2bf(u.w) << 16);
    ((uint2*)featsb)[i] = make_uint2(lo, hi);
  } else {
    const int i = (b - 4096) * 256 + t;  // < CFEAT*CFEAT/4 == NPTS
    const uint4 u = ((const uint4*)Wm)[i];
    const uint32_t lo = f2bf(u.x) | (f2bf(u.y) << 16);
    const uint32_t hi = f2bf(u.z) | (f2bf(u.w) << 16);
    ((uint2*)Wb)[i] = make_uint2(lo, hi);
    const int cx = cell1d(pts[3 * i]), cy = cell1d(pts[3 * i + 1]), cz = cell1d(pts[3 * i + 2]);
    atomicAdd(&cellcnt[(cz * NC + cy) * NC + cx], 1u);
  }
}

// ---------------------------------------------------------------------------
// Kb: exclusive scan of cellcnt -> cellstart[0..NCELLS]. Single block 1024,
// 16 elements/thread (4x uint4 + per-thread local prefix): 3 chunks total.
// ---------------------------------------------------------------------------
__global__ __launch_bounds__(1024) void k_scan(const uint32_t* __restrict__ hist,
                                               uint32_t* __restrict__ start, int n) {
  __shared__ uint32_t wsum[16];
  __shared__ uint32_t carry;
  const int t = threadIdx.x, wv = t >> 6, ln = t & 63;
  if (t == 0) carry = 0;
  __syncthreads();
  const int nq = n >> 2;
  for (int qb = 0; qb < nq; qb += 4096) {
    uint4 v[4];
    uint32_t psum[4];
    uint32_t tot = 0;
    #pragma unroll
    for (int k = 0; k < 4; ++k) {
      const int i4 = qb + t * 4 + k;
      v[k] = (i4 < nq) ? ((const uint4*)hist)[i4] : make_uint4(0, 0, 0, 0);
      psum[k] = tot;
      tot += v[k].x + v[k].y + v[k].z + v[k].w;
    }
    uint32_t s = tot;
    #pragma unroll
    for (int off = 1; off < 64; off <<= 1) {
      uint32_t o = __shfl_up(s, off, 64);
      if (ln >= off) s += o;
    }
    if (ln == 63) wsum[wv] = s;
    const uint32_t cbase = carry;
    __syncthreads();
    uint32_t woff = 0;
    for (int w = 0; w < wv; ++w) woff += wsum[w];
    const uint32_t base = cbase + woff + s - tot;
    #pragma unroll
    for (int k = 0; k < 4; ++k) {
      const int i4 = qb + t * 4 + k;
      if (i4 < nq) {
        const uint32_t e = base + psum[k];
        ((uint4*)start)[i4] =
            make_uint4(e, e + v[k].x, e + v[k].x + v[k].y, e + v[k].x + v[k].y + v[k].z);
      }
    }
    __syncthreads();
    if (t == 1023) carry = base + tot;
    __syncthreads();
  }
  if (t == 0) start[n] = carry;
}

// ---------------------------------------------------------------------------
// Kc: scatter points into cell-sorted order. sortedpts[pos] = (x,y,z,idx bits);
// sortedq[pos] = idx (spatially-sorted query order).
// ---------------------------------------------------------------------------
__global__ __launch_bounds__(256) void k_scatter(const float* __restrict__ pts,
                                                 const uint32_t* __restrict__ cellstart,
                                                 uint32_t* __restrict__ cellptr,
                                                 uint32_t* __restrict__ sortedq,
                                                 float4* __restrict__ sortedpts) {
  const int i = blockIdx.x * 256 + threadIdx.x;
  const float x = pts[3 * i], y = pts[3 * i + 1], z = pts[3 * i + 2];
  const int c = (cell1d(z) * NC + cell1d(y)) * NC + cell1d(x);
  const uint32_t pos = cellstart[c] + atomicAdd(&cellptr[c], 1u);
  sortedq[pos] = (uint32_t)i;
  sortedpts[pos] = make_float4(x, y, z, __uint_as_float((uint32_t)i));
}

// ---------------------------------------------------------------------------
// K1 (fused filter+select+pool): one wave per query, queries in sorted order.
// Phase F: cell-list ball query over a CONCATENATED virtual index space of
//   the 9 neighbor x-runs (full-lane iterations; candidate visit order is
//   identical to the per-row loop -> bit-identical selection).
// Phase S: 32-smallest set via 128-bucket d2 histogram rank-select; boundary
//   bucket resolved by (32-m) wave-argmins on exact fp64 keys.
// Phase P: max-pool 32 selected bf16 feature rows -> pooledb[q].
// ---------------------------------------------------------------------------
__global__ __launch_bounds__(256) void k_fsp(const uint32_t* __restrict__ sortedq,
                                             const uint32_t* __restrict__ cellstart,
                                             const float4* __restrict__ sortedpts,
                                             const uint16_t* __restrict__ featsb,
                                             uint16_t* __restrict__ pooledb) {
  __shared__ uint64_t keys[4][256];
  __shared__ uint32_t hist[4][NBUCK];
  __shared__ uint32_t sids[4][KNN];
  const int t = threadIdx.x;
  const int w = t >> 6;
  const int lane = t & 63;
  const uint64_t ltmask = (1ull << lane) - 1ull;
  const int q = (int)sortedq[blockIdx.x * 4 + w];
  const float4 qp = sortedpts[blockIdx.x * 4 + w];
  const float qx = qp.x, qy = qp.y, qz = qp.z;
  const int icx = cell1d(qx), icy = cell1d(qy), icz = cell1d(qz);
  const int x0 = max(icx - 1, 0), x1 = min(icx + 1, NC - 1);
  // ---- Phase F: build 9-row concatenated ranges (registers, full unroll) ----
  int S[9], E[9];
  #pragma unroll
  for (int r = 0; r < 9; ++r) {
    const int cz = icz + (r / 3) - 1;
    const int cy = icy + (r % 3) - 1;
    const bool ok = (cz >= 0) && (cz < NC) && (cy >= 0) && (cy < NC);
    const int rb = ((ok ? cz : 0) * NC + (ok ? cy : 0)) * NC;
    const int s = (int)cellstart[rb + x0];
    const int e = (int)cellstart[rb + x1 + 1];
    S[r] = ok ? s : 0;
    E[r] = ok ? e : 0;
  }
  int PRE[10], OFF[9];
  PRE[0] = 0;
  #pragma unroll
  for (int r = 0; r < 9; ++r) {
    PRE[r + 1] = PRE[r] + (E[r] - S[r]);
    OFF[r] = S[r] - PRE[r];
  }
  const int total = PRE[9];
  uint32_t c_run = 0;
  for (int v0 = 0; v0 < total; v0 += 64) {
    const int v = v0 + lane;
    int addr = v + OFF[0];
    #pragma unroll
    for (int r = 1; r < 9; ++r) addr = (v >= PRE[r]) ? (v + OFF[r]) : addr;
    const int ia = min(addr, NPTS - 1);
    const float4 p = sortedpts[ia];
    const float dxf = qx - p.x, dyf = qy - p.y, dzf = qz - p.z;
    const float d2 = __fmaf_rn(dxf, dxf, __fmaf_rn(dyf, dyf, __fmul_rn(dzf, dzf)));
    bool pass = (v < total) && (d2 <= RR_HI);
    uint64_t key = 0;
    if (pass) {
      const double ddx = (double)qx - (double)p.x;
      const double ddy = (double)qy - (double)p.y;
      const double ddz = (double)qz - (double)p.z;
      const double dd2 = fma(ddx, ddx, fma(ddy, ddy, ddz * ddz));
      pass = (dd2 <= 0.3 * 0.3);  // exact double threshold, as numpy
      key = ((uint64_t)__double_as_longlong(dd2) & ~0x3FFFull) |
            (uint64_t)__float_as_uint(p.w);
    }
    const uint64_t mask = __ballot(pass);
    if (pass) {
      const uint32_t pos = c_run + (uint32_t)__popcll(mask & ltmask);
      if (pos < 256u) keys[w][pos] = key;
    }
    c_run += (uint32_t)__popcll(mask);
  }
  const int c = (int)min(c_run, 256u);
  // ---- Phase S ----
  if (c <= KNN) {
    if (lane < KNN) sids[w][lane] = (lane < c) ? (uint32_t)(keys[w][lane] & 0x3FFFull) : 0u;
  } else {
    const uint64_t INVALID = ~0ull;
    uint64_t k0 = (lane < c) ? keys[w][lane] : INVALID;
    uint64_t k1 = (lane + 64 < c) ? keys[w][lane + 64] : INVALID;
    uint64_t k2 = (lane + 128 < c) ? keys[w][lane + 128] : INVALID;
    uint64_t k3 = (lane + 192 < c) ? keys[w][lane + 192] : INVALID;
    hist[w][lane] = 0;
    hist[w][lane + 64] = 0;
    int b0 = 999, b1 = 999, b2 = 999, b3 = 999;
    const float bs = 128.0f / 0.09f;
    if (k0 != INVALID) { b0 = min(NBUCK - 1, (int)((float)__longlong_as_double((long long)(k0 & ~0x3FFFull)) * bs)); atomicAdd(&hist[w][b0], 1u); }
    if (k1 != INVALID) { b1 = min(NBUCK - 1, (int)((float)__longlong_as_double((long long)(k1 & ~0x3FFFull)) * bs)); atomicAdd(&hist[w][b1], 1u); }
    if (k2 != INVALID) { b2 = min(NBUCK - 1, (int)((float)__longlong_as_double((long long)(k2 & ~0x3FFFull)) * bs)); atomicAdd(&hist[w][b2], 1u); }
    if (k3 != INVALID) { b3 = min(NBUCK - 1, (int)((float)__longlong_as_double((long long)(k3 & ~0x3FFFull)) * bs)); atomicAdd(&hist[w][b3], 1u); }
    const uint32_t h0 = hist[w][2 * lane], h1 = hist[w][2 * lane + 1];
    const uint32_t tot = h0 + h1;
    uint32_t s = tot;
    #pragma unroll
    for (int off = 1; off < 64; off <<= 1) {
      uint32_t o = __shfl_up(s, off, 64);
      if (lane >= off) s += o;
    }
    const uint32_t C0 = s - tot + h0;
    const uint32_t C1 = s - tot + h0 + h1;
    const uint64_t me = __ballot(C0 >= KNN);
    const uint64_t mo = __ballot(C1 >= KNN);
    const int be = me ? 2 * (__ffsll((unsigned long long)me) - 1) : (1 << 30);
    const int bo = mo ? 2 * (__ffsll((unsigned long long)mo) - 1) + 1 : (1 << 30);
    const int bstar = min(be, bo);
    const uint32_t mval_mine = (bstar & 1) ? (C1 - h1) : (C0 - h0);
    const uint32_t m = (uint32_t)__shfl((int)mval_mine, bstar >> 1, 64);
    uint32_t wpos = 0;
    {
      bool win = (b0 < bstar);
      uint64_t bm = __ballot(win);
      if (win) sids[w][wpos + (uint32_t)__popcll(bm & ltmask)] = (uint32_t)(k0 & 0x3FFFull);
      wpos += (uint32_t)__popcll(bm);
      win = (b1 < bstar); bm = __ballot(win);
      if (win) sids[w][wpos + (uint32_t)__popcll(bm & ltmask)] = (uint32_t)(k1 & 0x3FFFull);
      wpos += (uint32_t)__popcll(bm);
      win = (b2 < bstar); bm = __ballot(win);
      if (win) sids[w][wpos + (uint32_t)__popcll(bm & ltmask)] = (uint32_t)(k2 & 0x3FFFull);
      wpos += (uint32_t)__popcll(bm);
      win = (b3 < bstar); bm = __ballot(win);
      if (win) sids[w][wpos + (uint32_t)__popcll(bm & ltmask)] = (uint32_t)(k3 & 0x3FFFull);
      wpos += (uint32_t)__popcll(bm);
    }
    uint64_t e0 = (b0 == bstar) ? k0 : INVALID;
    uint64_t e1 = (b1 == bstar) ? k1 : INVALID;
    uint64_t e2 = (b2 == bstar) ? k2 : INVALID;
    uint64_t e3 = (b3 == bstar) ? k3 : INVALID;
    const int need = KNN - (int)m;
    for (int it = 0; it < need; ++it) {
      uint64_t a = e0 < e1 ? e0 : e1;
      uint64_t b = e2 < e3 ? e2 : e3;
      uint64_t mn = a < b ? a : b;
      #pragma unroll
      for (int off = 1; off < 64; off <<= 1) {
        uint64_t o = (uint64_t)__shfl_xor((unsigned long long)mn, off, 64);
        mn = o < mn ? o : mn;
      }
      if (e0 == mn) e0 = INVALID;
      else if (e1 == mn) e1 = INVALID;
      else if (e2 == mn) e2 = INVALID;
      else if (e3 == mn) e3 = INVALID;
      if (lane == 0) sids[w][m + it] = (uint32_t)(mn & 0x3FFFull);
    }
  }
  // ---- Phase P ----
  float m0 = -3.0e38f, m1 = -3.0e38f, m2 = -3.0e38f, m3 = -3.0e38f;
  #pragma unroll 8
  for (int k = 0; k < KNN; ++k) {
    const uint32_t idx = sids[w][k];
    const uint2 v = *(const uint2*)(featsb + (size_t)idx * CFEAT + lane * 4);
    m0 = fmaxf(m0, __uint_as_float(v.x << 16));
    m1 = fmaxf(m1, __uint_as_float(v.x & 0xffff0000u));
    m2 = fmaxf(m2, __uint_as_float(v.y << 16));
    m3 = fmaxf(m3, __uint_as_float(v.y & 0xffff0000u));
  }
  const uint32_t lo = (__float_as_uint(m0) >> 16) | (__float_as_uint(m1) & 0xffff0000u);
  const uint32_t hi = (__float_as_uint(m2) >> 16) | (__float_as_uint(m3) & 0xffff0000u);
  ((uint2*)pooledb)[(size_t)q * 64 + lane] = make_uint2(lo, hi);
}

// ---------------------------------------------------------------------------
// K4: h = pooled @ W^T + b ; LayerNorm ; ReLU -> fp32 out.
// M-tile 64, N = 256, K = 256 in 8 steps of 32; wave w owns N-slice
// [64w,64w+64) as 4x4 mfma_f32_16x16x32_bf16 tiles.
// ---------------------------------------------------------------------------
__global__ __launch_bounds__(256) void k_gemm_ln(const uint16_t* __restrict__ pooledb,
                                                 const uint16_t* __restrict__ Wb,
                                                 const float* __restrict__ bias,
                                                 const float* __restrict__ gamma,
                                                 const float* __restrict__ beta,
                                                 float* __restrict__ out) {
  __shared__ uint16_t As[64 * 264];
  __shared__ uint16_t Bs[256 * 40];
  __shared__ float red1[4][64];
  __shared__ float red2[4][64];
  __shared__ float mu_s[64];
  __shared__ float rs_s[64];
  const int t = threadIdx.x;
  const int wave = t >> 6;
  const int lane = t & 63;
  const int quad = lane >> 4;
  const int l15 = lane & 15;
  const int m0 = blockIdx.x * 64;
  {
    const int m = t >> 2, qtr = t & 3;
    const uint4* src = (const uint4*)(pooledb + (size_t)(m0 + m) * 256 + qtr * 64);
    uint4* dst = (uint4*)(As + m * 264 + qtr * 64);
    #pragma unroll
    for (int i = 0; i < 8; ++i) dst[i] = src[i];
  }
  floatx4 acc[4][4];
  #pragma unroll
  for (int mi = 0; mi < 4; ++mi)
    #pragma unroll
    for (int ni = 0; ni < 4; ++ni)
      acc[mi][ni] = (floatx4){0.f, 0.f, 0.f, 0.f};

  for (int step = 0; step < 8; ++step) {
    __syncthreads();
    {
      const uint4* src = (const uint4*)(Wb + (size_t)t * 256 + step * 32);
      uint4* dst = (uint4*)(Bs + t * 40);
      #pragma unroll
      for (int i = 0; i < 4; ++i) dst[i] = src[i];
    }
    __syncthreads();
    short8 a[4], b[4];
    #pragma unroll
    for (int mi = 0; mi < 4; ++mi)
      a[mi] = *(const short8*)(As + (mi * 16 + l15) * 264 + step * 32 + quad * 8);
    #pragma unroll
    for (int ni = 0; ni < 4; ++ni)
      b[ni] = *(const short8*)(Bs + (wave * 64 + ni * 16 + l15) * 40 + quad * 8);
    #pragma unroll
    for (int mi = 0; mi < 4; ++mi)
      #pragma unroll
      for (int ni = 0; ni < 4; ++ni)
        acc[mi][ni] = __builtin_amdgcn_mfma_f32_16x16x32_bf16(a[mi], b[ni], acc[mi][ni], 0, 0, 0);
  }

  float bcol[4], gcol[4], zcol[4];
  #pragma unroll
  for (int ni = 0; ni < 4; ++ni) {
    const int col = wave * 64 + ni * 16 + l15;
    bcol[ni] = bias[col];
    gcol[ni] = gamma[col];
    zcol[ni] = beta[col];
  }
  #pragma unroll
  for (int mi = 0; mi < 4; ++mi)
    #pragma unroll
    for (int ni = 0; ni < 4; ++ni)
      #pragma unroll
      for (int r = 0; r < 4; ++r)
        acc[mi][ni][r] += bcol[ni];
  #pragma unroll
  for (int mi = 0; mi < 4; ++mi) {
    #pragma unroll
    for (int r = 0; r < 4; ++r) {
      const float v0 = acc[mi][0][r], v1 = acc[mi][1][r], v2 = acc[mi][2][r], v3 = acc[mi][3][r];
      float s1 = v0 + v1 + v2 + v3;
      float s2 = v0 * v0 + v1 * v1 + v2 * v2 + v3 * v3;
      #pragma unroll
      for (int off = 1; off < 16; off <<= 1) {
        s1 += __shfl_xor(s1, off, 64);
        s2 += __shfl_xor(s2, off, 64);
      }
      if (l15 == 0) {
        const int row = mi * 16 + quad * 4 + r;
        red1[wave][row] = s1;
        red2[wave][row] = s2;
      }
    }
  }
  __syncthreads();
  if (t < 64) {
    const float s1 = red1[0][t] + red1[1][t] + red1[2][t] + red1[3][t];
    const float s2 = red2[0][t] + red2[1][t] + red2[2][t] + red2[3][t];
    const float mu = s1 * (1.0f / 256.0f);
    const float var = s2 * (1.0f / 256.0f) - mu * mu;
    mu_s[t] = mu;
    rs_s[t] = 1.0f / sqrtf(var + 1e-5f);
  }
  __syncthreads();
  #pragma unroll
  for (int mi = 0; mi < 4; ++mi) {
    #pragma unroll
    for (int r = 0; r < 4; ++r) {
      const int row = mi * 16 + quad * 4 + r;
      const float mu = mu_s[row], rs = rs_s[row];
      #pragma unroll
      for (int ni = 0; ni < 4; ++ni) {
        float y = (acc[mi][ni][r] - mu) * rs * gcol[ni] + zcol[ni];
        out[(size_t)(m0 + row) * 256 + wave * 64 + ni * 16 + l15] = fmaxf(y, 0.0f);
      }
    }
  }
}

// ---------------------------------------------------------------------------
// ws: [featsb 8M][Wb 128K][pooledb 8M][cellcnt][cellptr][cellstart][sortedq]
//     [sortedpts]
// ---------------------------------------------------------------------------
extern "C" void kernel_launch(void* const* d_in, const int* in_sizes, int n_in,
                              void* d_out, int out_size, void* d_ws, size_t ws_size,
                              hipStream_t stream) {
  (void)in_sizes; (void)n_in; (void)out_size; (void)ws_size;
  const float* pts   = (const float*)d_in[0];
  // d_in[1] = src_masks (all True) -- unused
  const float* feats = (const float*)d_in[2];
  const float* Wm    = (const float*)d_in[3];
  const float* bias  = (const float*)d_in[4];
  const float* gamma = (const float*)d_in[5];
  const float* beta  = (const float*)d_in[6];
  float* out = (float*)d_out;

  uint8_t* ws = (uint8_t*)d_ws;
  uint16_t* featsb    = (uint16_t*)ws;                      // @0        8 MB
  uint16_t* Wb        = (uint16_t*)(ws + 8388608);          // 128 KB
  uint16_t* pooledb   = (uint16_t*)(ws + 8519680);          // 8 MB
  uint32_t* cellcnt   = (uint32_t*)(ws + 16908288);         // 157440 B (NCELLS*4 pad)
  uint32_t* cellptr   = (uint32_t*)(ws + 17065728);         // 157440 B
  uint32_t* cellstart = (uint32_t*)(ws + 17223168);         // 157440 B ((NCELLS+1)*4 pad)
  uint32_t* sortedq   = (uint32_t*)(ws + 17380608);         // 64 KB
  float4*   sortedpts = (float4*)(ws + 17446144);           // 256 KB -> end 17708288

  (void)hipMemsetAsync(cellcnt, 0, 2 * 157440, stream);  // cellcnt + cellptr
  k_prep<<<4160, 256, 0, stream>>>(feats, featsb, Wm, Wb, pts, cellcnt);
  k_scan<<<1, 1024, 0, stream>>>(cellcnt, cellstart, NCELLS);
  k_scatter<<<64, 256, 0, stream>>>(pts, cellstart, cellptr, sortedq, sortedpts);
  k_fsp<<<4096, 256, 0, stream>>>(sortedq, cellstart, sortedpts, featsb, pooledb);
  k_gemm_ln<<<256, 256, 0, stream>>>(pooledb, Wb, bias, gamma, beta, out);
}